// Round 2
// baseline (3286.912 us; speedup 1.0000x reference)
//
#include <hip/hip_runtime.h>
#include <stdint.h>

// ---------------- problem constants ----------------
#define B_  8
#define T_  2048
#define D_  1024
#define H_  16
#define M_  (B_*T_)                 // 16384 rows
#define LOG_W_SCALE (-0.6065306597126334f)
#define GN_EPS (64.0e-5f)           // HD * 1e-5

typedef short short8 __attribute__((ext_vector_type(8)));
typedef float f32x4_t __attribute__((ext_vector_type(4)));

static __device__ __forceinline__ short f2bf(float f) {
  uint32_t u = __builtin_bit_cast(uint32_t, f);
  u += 0x7fffu + ((u >> 16) & 1u);
  return (short)(u >> 16);
}
static __device__ __forceinline__ float bf2f(ushort u) {
  uint32_t x = ((uint32_t)u) << 16;
  return __builtin_bit_cast(float, x);
}
static __device__ __forceinline__ float sigmf_(float x) { return 1.0f / (1.0f + expf(-x)); }

// ---------------- ws layout (bytes) ----------------
#define OFF_WrT    0ULL
#define OFF_WkT    2097152ULL
#define OFF_WvT    4194304ULL
#define OFF_WoT    6291456ULL
#define OFF_w1T    8388608ULL
#define OFF_a1T    8519680ULL
#define OFF_v1T    8650752ULL
#define OFF_g1T    8716288ULL
#define OFF_w2T    9043968ULL
#define OFF_a2T    9175040ULL
#define OFF_v2T    9306112ULL
#define OFF_g2T    9371648ULL
#define OFF_RB     16777216ULL      // r bf16 [M][1024] 32MiB
#define OFF_KB     50331648ULL      // k bf16
#define OFF_VB     83886080ULL      // v raw bf16
#define OFF_A2O    117440512ULL     // a-lora out bf16
#define OFF_V2O    150994944ULL     // v-lora out bf16
#define OFF_GIO    184549376ULL     // g bf16; epilogue overwrites in place with gated o_n
#define OFF_D1B    218103808ULL
#define OFF_A1B    220200960ULL
#define OFF_V1B    222298112ULL
#define OFF_G1B    223346688ULL
#define WS_NEED    228589568ULL     // ~218 MiB

// ---------------- transpose+convert: f32 [K][N] -> bf16 [N][K] ----------------
struct TransDesc { const float* src; ushort* dst; int K, N, blk0, ntn; };
struct TransPack { TransDesc d[12]; };

__global__ __launch_bounds__(256) void trans_kernel(TransPack p) {
  __shared__ float tile[32][33];
  int bid = blockIdx.x;
  int mi = 0;
  #pragma unroll
  for (int i = 1; i < 12; i++) if (bid >= p.d[i].blk0) mi = i;
  TransDesc d = p.d[mi];
  int lb = bid - d.blk0;
  int tn = lb % d.ntn, tk = lb / d.ntn;
  int tx = threadIdx.x & 31, ty = threadIdx.x >> 5;
  #pragma unroll
  for (int i = 0; i < 4; i++) {
    int k = tk*32 + ty + i*8, n = tn*32 + tx;
    float v = (k < d.K && n < d.N) ? d.src[(size_t)k*d.N + n] : 0.f;
    tile[ty + i*8][tx] = v;
  }
  __syncthreads();
  #pragma unroll
  for (int i = 0; i < 4; i++) {
    int n = tn*32 + ty + i*8, k = tk*32 + tx;
    if (n < d.N && k < d.K) d.dst[(size_t)n*d.K + k] = (ushort)f2bf(tile[tx][ty + i*8]);
  }
}

// ---------------- GEMM: C[M][N] = A[M][K] @ B[K][N], B given as Bt[N][K] bf16 ----------------
// AMIX: A built on the fly from x (token-shift lerp, per-feature coef), K=1024.
// OMODE: 0 = f32 out, 1 = bf16 out, 2 = bf16(tanh), 3 = bf16(sigmoid)
template<bool AMIX, int OMODE>
__global__ __launch_bounds__(256) void gemm_kernel(
    const float* __restrict__ X, const float* __restrict__ xxc,
    const ushort* __restrict__ Abf,
    const ushort* __restrict__ Bt,
    void* __restrict__ Cout, int N, int K)
{
  __shared__ ushort As[128*64];
  __shared__ ushort Bs[128*64];
  int tid = threadIdx.x;
  int bm = blockIdx.y, bn = blockIdx.x;
  int wave = tid >> 6, lane = tid & 63;
  int wr = wave >> 1, wc = wave & 1;
  f32x4_t acc[4][4];
  #pragma unroll
  for (int i = 0; i < 4; i++)
    #pragma unroll
    for (int j = 0; j < 4; j++) acc[i][j] = (f32x4_t){0.f,0.f,0.f,0.f};

  int srow = tid >> 1;
  int scol = (tid & 1) * 32;
  int grow = bm*128 + srow;
  int gbn  = bn*128 + srow;

  for (int k0 = 0; k0 < K; k0 += 64) {
    if constexpr (AMIX) {
      const float* xr = X + (size_t)grow*1024 + k0 + scol;
      bool sh = (grow & (T_-1)) != 0;
      const float* xs = sh ? (xr - 1024) : xr;   // safe address always
      float msk = sh ? 1.f : 0.f;
      const float* cf = xxc + k0 + scol;
      #pragma unroll
      for (int i = 0; i < 4; i++) {
        float4 xa = *(const float4*)(xr + i*8);
        float4 xb = *(const float4*)(xr + i*8 + 4);
        float4 s4 = *(const float4*)(xs + i*8);
        float4 s5 = *(const float4*)(xs + i*8 + 4);
        float4 ca = *(const float4*)(cf + i*8);
        float4 cb = *(const float4*)(cf + i*8 + 4);
        short8 w;
        w[0]=f2bf(xa.x + (s4.x*msk - xa.x)*ca.x);
        w[1]=f2bf(xa.y + (s4.y*msk - xa.y)*ca.y);
        w[2]=f2bf(xa.z + (s4.z*msk - xa.z)*ca.z);
        w[3]=f2bf(xa.w + (s4.w*msk - xa.w)*ca.w);
        w[4]=f2bf(xb.x + (s5.x*msk - xb.x)*cb.x);
        w[5]=f2bf(xb.y + (s5.y*msk - xb.y)*cb.y);
        w[6]=f2bf(xb.z + (s5.z*msk - xb.z)*cb.z);
        w[7]=f2bf(xb.w + (s5.w*msk - xb.w)*cb.w);
        *(short8*)&As[srow*64 + scol + i*8] = w;
      }
    } else {
      const ushort* ap = Abf + (size_t)grow*K + k0 + scol;
      #pragma unroll
      for (int i = 0; i < 4; i++) {
        uint4 u = make_uint4(0,0,0,0);
        if (k0 + scol + i*8 + 8 <= K) u = *(const uint4*)(ap + i*8);
        *(uint4*)&As[srow*64 + scol + i*8] = u;
      }
    }
    {
      const ushort* bp = Bt + (size_t)gbn*K + k0 + scol;
      #pragma unroll
      for (int i = 0; i < 4; i++) {
        uint4 u = make_uint4(0,0,0,0);
        if (gbn < N && (k0 + scol + i*8 + 8 <= K)) u = *(const uint4*)(bp + i*8);
        *(uint4*)&Bs[srow*64 + scol + i*8] = u;
      }
    }
    __syncthreads();
    int l15 = lane & 15, kof = (lane >> 4) * 8;
    #pragma unroll
    for (int ks = 0; ks < 2; ks++) {
      short8 af[4], bfv[4];
      #pragma unroll
      for (int f = 0; f < 4; f++)
        af[f] = *(const short8*)&As[(wr*64 + f*16 + l15)*64 + ks*32 + kof];
      #pragma unroll
      for (int f = 0; f < 4; f++)
        bfv[f] = *(const short8*)&Bs[(wc*64 + f*16 + l15)*64 + ks*32 + kof];
      #pragma unroll
      for (int fr = 0; fr < 4; fr++)
        #pragma unroll
        for (int fc = 0; fc < 4; fc++)
          acc[fr][fc] = __builtin_amdgcn_mfma_f32_16x16x32_bf16(af[fr], bfv[fc], acc[fr][fc], 0, 0, 0);
    }
    __syncthreads();
  }
  int l15 = lane & 15, rg = lane >> 4;
  #pragma unroll
  for (int fr = 0; fr < 4; fr++)
    #pragma unroll
    for (int fc = 0; fc < 4; fc++) {
      int col = bn*128 + wc*64 + fc*16 + l15;
      if (col < N) {
        #pragma unroll
        for (int j = 0; j < 4; j++) {
          int row = bm*128 + wr*64 + fr*16 + rg*4 + j;
          float v = acc[fr][fc][j];
          if constexpr (OMODE == 2) v = tanhf(v);
          if constexpr (OMODE == 3) v = sigmf_(v);
          if constexpr (OMODE == 0) ((float*)Cout)[(size_t)row*N + col] = v;
          else ((ushort*)Cout)[(size_t)row*N + col] = (ushort)f2bf(v);
        }
      }
    }
}

// ---------------- scan with inline operand assembly; 1 block per (b,h), 4 waves ----------------
// wave w owns state columns [16w,16w+16); lane = row; S[16] f32 regs per lane.
__global__ __launch_bounds__(256, 1) void scan_kernel(
    const ushort* __restrict__ rb, const ushort* __restrict__ kb, const ushort* __restrict__ vb,
    const ushort* __restrict__ d2, const ushort* __restrict__ a2o, const ushort* __restrict__ v2o,
    const float* __restrict__ vfirst,
    const float* __restrict__ w0, const float* __restrict__ a0, const float* __restrict__ v0,
    const float* __restrict__ kkv, const float* __restrict__ kav,
    float* __restrict__ o)
{
  __shared__ float bufs[6][8][64];   // r,e,k,v,a,b
  __shared__ float red1[256];
  __shared__ float red2[256];
  int tid = threadIdx.x;
  int bh = blockIdx.x;
  int b = bh >> 4, h = bh & 15;
  int wave = tid >> 6, lane = tid & 63;
  int c0 = wave * 16;
  float S[16];
  #pragma unroll
  for (int i = 0; i < 16; i++) S[i] = 0.f;
  // per-lane channel constants (c = lane within head)
  int hc = h*64 + lane;
  float kkc = kkv[hc], kac = kav[hc], w0c = w0[hc], a0c = a0[hc], v0c = v0[hc];

  for (int t0 = 0; t0 < T_; t0 += 8) {
    #pragma unroll
    for (int j = 0; j < 2; j++) {
      int tt = wave + j*4;
      size_t gi = ((size_t)(b*T_ + t0 + tt) * H_ + h) * 64 + lane;
      float kv_ = bf2f(kb[gi]);
      float rv_ = bf2f(rb[gi]);
      float vv_ = bf2f(vb[gi]);
      float dd  = bf2f(d2[gi]);
      float av  = bf2f(a2o[gi]);
      float vo  = bf2f(v2o[gi]);
      float vf  = vfirst[gi];
      float kp = kv_ * kkc;
      float ss = kp * kp;
      ss += __shfl_xor(ss, 1);  ss += __shfl_xor(ss, 2);
      ss += __shfl_xor(ss, 4);  ss += __shfl_xor(ss, 8);
      ss += __shfl_xor(ss, 16); ss += __shfl_xor(ss, 32);
      float inv = 1.0f / fmaxf(sqrtf(ss), 1e-12f);
      float asig = sigmf_(a0c + av);
      float e = expf(LOG_W_SCALE * sigmf_(w0c + dd));
      float kn = kv_ * (1.f + (asig - 1.f) * kac);
      float vl = vv_ + (vf - vv_) * sigmf_(v0c + vo);
      float kkn = kp * inv;
      bufs[0][tt][lane] = rv_;
      bufs[1][tt][lane] = e;
      bufs[2][tt][lane] = kn;
      bufs[3][tt][lane] = vl;
      bufs[4][tt][lane] = -kkn;
      bufs[5][tt][lane] = kkn * asig;
    }
    __syncthreads();
    for (int tt = 0; tt < 8; tt++) {
      const float4* A4 = (const float4*)&bufs[4][tt][c0];
      float p = 0.f;
      #pragma unroll
      for (int j = 0; j < 4; j++) {
        float4 a4 = A4[j];
        p += S[j*4+0]*a4.x + S[j*4+1]*a4.y + S[j*4+2]*a4.z + S[j*4+3]*a4.w;
      }
      red1[wave*64 + lane] = p;
      __syncthreads();
      float sa = red1[lane] + red1[64+lane] + red1[128+lane] + red1[192+lane];
      float vi = bufs[3][tt][lane];
      const float4* E4 = (const float4*)&bufs[1][tt][c0];
      const float4* K4 = (const float4*)&bufs[2][tt][c0];
      const float4* B4 = (const float4*)&bufs[5][tt][c0];
      const float4* R4 = (const float4*)&bufs[0][tt][c0];
      float op = 0.f;
      #pragma unroll
      for (int j = 0; j < 4; j++) {
        float4 e4 = E4[j], k4 = K4[j], b4 = B4[j], r4 = R4[j];
        float s;
        s = S[j*4+0]*e4.x + sa*b4.x + vi*k4.x; S[j*4+0]=s; op += s*r4.x;
        s = S[j*4+1]*e4.y + sa*b4.y + vi*k4.y; S[j*4+1]=s; op += s*r4.y;
        s = S[j*4+2]*e4.z + sa*b4.z + vi*k4.z; S[j*4+2]=s; op += s*r4.z;
        s = S[j*4+3]*e4.w + sa*b4.w + vi*k4.w; S[j*4+3]=s; op += s*r4.w;
      }
      red2[wave*64 + lane] = op;
      __syncthreads();
      if (wave == 0) {
        float oo = red2[lane] + red2[64+lane] + red2[128+lane] + red2[192+lane];
        o[((size_t)(b*T_ + t0 + tt) * H_ + h) * 64 + lane] = oo;
      }
    }
    __syncthreads();   // bufs WAR before next staging
  }
}

// ---------------- epilogue: GroupNorm + bonus + gate -> bf16 (in place over g buffer) ----------------
__global__ __launch_bounds__(256) void epilogue_kernel(
    const float* __restrict__ o,
    const ushort* __restrict__ rb, const ushort* __restrict__ kb, const ushort* __restrict__ vb,
    const ushort* __restrict__ a2o, const ushort* __restrict__ v2o,
    const float* __restrict__ vfirst,
    ushort* g_io,                                   // read g, write gated o_n (same buffer)
    const float* __restrict__ a0, const float* __restrict__ v0, const float* __restrict__ kav,
    const float* __restrict__ rkv,
    const float* __restrict__ gnw, const float* __restrict__ gnb)
{
  int row = blockIdx.x;
  int tid = threadIdx.x;
  int d0 = tid * 4;
  size_t gi = (size_t)row * D_ + d0;
  // load g FIRST (we overwrite it at the end)
  ushort4 gu = *(const ushort4*)(g_io + gi);
  float4 o4 = *(const float4*)(o + gi);
  ushort4 ru = *(const ushort4*)(rb + gi);
  ushort4 ku = *(const ushort4*)(kb + gi);
  ushort4 vu = *(const ushort4*)(vb + gi);
  ushort4 au = *(const ushort4*)(a2o + gi);
  ushort4 wu = *(const ushort4*)(v2o + gi);
  float4 vf = *(const float4*)(vfirst + gi);
  float4 a04 = *(const float4*)(a0 + d0);
  float4 v04 = *(const float4*)(v0 + d0);
  float4 ka4 = *(const float4*)(kav + d0);
  float4 rk  = *(const float4*)(rkv + d0);   // rkv is [H][64] = [D]
  float4 gw  = *(const float4*)(gnw + d0);
  float4 gb  = *(const float4*)(gnb + d0);

  // GroupNorm stats over head (16 threads per head within a wave)
  float s1 = o4.x + o4.y + o4.z + o4.w;
  float s2 = o4.x*o4.x + o4.y*o4.y + o4.z*o4.z + o4.w*o4.w;
  s1 += __shfl_xor(s1, 1, 16); s2 += __shfl_xor(s2, 1, 16);
  s1 += __shfl_xor(s1, 2, 16); s2 += __shfl_xor(s2, 2, 16);
  s1 += __shfl_xor(s1, 4, 16); s2 += __shfl_xor(s2, 4, 16);
  s1 += __shfl_xor(s1, 8, 16); s2 += __shfl_xor(s2, 8, 16);
  float mean = s1 * (1.f/64.f);
  float var  = s2 * (1.f/64.f) - mean*mean;
  float rstd = rsqrtf(var + GN_EPS);

  // recompute k_new, v_lerp
  float r0=bf2f(ru.x), r1=bf2f(ru.y), r2=bf2f(ru.z), r3=bf2f(ru.w);
  float k0=bf2f(ku.x), k1=bf2f(ku.y), k2=bf2f(ku.z), k3=bf2f(ku.w);
  float v0_=bf2f(vu.x), v1_=bf2f(vu.y), v2_=bf2f(vu.z), v3_=bf2f(vu.w);
  float a0_=sigmf_(a04.x+bf2f(au.x)), a1_=sigmf_(a04.y+bf2f(au.y));
  float a2_=sigmf_(a04.z+bf2f(au.z)), a3_=sigmf_(a04.w+bf2f(au.w));
  float kn0=k0*(1.f+(a0_-1.f)*ka4.x), kn1=k1*(1.f+(a1_-1.f)*ka4.y);
  float kn2=k2*(1.f+(a2_-1.f)*ka4.z), kn3=k3*(1.f+(a3_-1.f)*ka4.w);
  float sl;
  sl=sigmf_(v04.x+bf2f(wu.x)); float vl0=v0_+(vf.x-v0_)*sl;
  sl=sigmf_(v04.y+bf2f(wu.y)); float vl1=v1_+(vf.y-v1_)*sl;
  sl=sigmf_(v04.z+bf2f(wu.z)); float vl2=v2_+(vf.z-v2_)*sl;
  sl=sigmf_(v04.w+bf2f(wu.w)); float vl3=v3_+(vf.w-v3_)*sl;

  float bsum = r0*kn0*rk.x + r1*kn1*rk.y + r2*kn2*rk.z + r3*kn3*rk.w;
  bsum += __shfl_xor(bsum, 1, 16); bsum += __shfl_xor(bsum, 2, 16);
  bsum += __shfl_xor(bsum, 4, 16); bsum += __shfl_xor(bsum, 8, 16);

  float g0=bf2f(gu.x), g1=bf2f(gu.y), g2=bf2f(gu.z), g3=bf2f(gu.w);
  float ox = ((o4.x-mean)*rstd*gw.x + gb.x + bsum*vl0) * g0;
  float oy = ((o4.y-mean)*rstd*gw.y + gb.y + bsum*vl1) * g1;
  float oz = ((o4.z-mean)*rstd*gw.z + gb.z + bsum*vl2) * g2;
  float ow = ((o4.w-mean)*rstd*gw.w + gb.w + bsum*vl3) * g3;
  ushort4 u = make_ushort4((ushort)f2bf(ox),(ushort)f2bf(oy),(ushort)f2bf(oz),(ushort)f2bf(ow));
  *((ushort4*)(g_io + gi)) = u;
}

__global__ void marker_kernel(float* p, float v) { p[0] = v; }

// ---------------- launch ----------------
extern "C" void kernel_launch(void* const* d_in, const int* in_sizes, int n_in,
                              void* d_out, int out_size, void* d_ws, size_t ws_size,
                              hipStream_t stream) {
  float* dout = (float*)d_out;
  if (ws_size < WS_NEED) {   // failure marker encodes actual ws_size
    hipLaunchKernelGGL(marker_kernel, dim3(1), dim3(1), 0, stream, dout, (float)ws_size);
    return;
  }
  const float* x      = (const float*)d_in[0];
  const float* vfirst = (const float*)d_in[1];
  const float* xx     = (const float*)d_in[2];
  const float* w0v    = (const float*)d_in[9];
  const float* a0v    = (const float*)d_in[12];
  const float* v0v    = (const float*)d_in[15];
  const float* kkv    = (const float*)d_in[18];
  const float* kav    = (const float*)d_in[19];
  const float* rkv    = (const float*)d_in[20];
  const float* gnw    = (const float*)d_in[21];
  const float* gnb    = (const float*)d_in[22];

  char* ws = (char*)d_ws;
  ushort* WrT = (ushort*)(ws + OFF_WrT); ushort* WkT = (ushort*)(ws + OFF_WkT);
  ushort* WvT = (ushort*)(ws + OFF_WvT); ushort* WoT = (ushort*)(ws + OFF_WoT);
  ushort* w1T = (ushort*)(ws + OFF_w1T); ushort* a1T = (ushort*)(ws + OFF_a1T);
  ushort* v1T = (ushort*)(ws + OFF_v1T); ushort* g1T = (ushort*)(ws + OFF_g1T);
  ushort* w2T = (ushort*)(ws + OFF_w2T); ushort* a2T = (ushort*)(ws + OFF_a2T);
  ushort* v2T = (ushort*)(ws + OFF_v2T); ushort* g2T = (ushort*)(ws + OFF_g2T);
  ushort* rb  = (ushort*)(ws + OFF_RB);
  ushort* kb  = (ushort*)(ws + OFF_KB);
  ushort* vb  = (ushort*)(ws + OFF_VB);
  ushort* a2o = (ushort*)(ws + OFF_A2O);
  ushort* v2o = (ushort*)(ws + OFF_V2O);
  ushort* gio = (ushort*)(ws + OFF_GIO);
  ushort* d1b = (ushort*)(ws + OFF_D1B);
  ushort* a1b = (ushort*)(ws + OFF_A1B);
  ushort* v1b = (ushort*)(ws + OFF_V1B);
  ushort* g1b = (ushort*)(ws + OFF_G1B);
  // d_out borrowed as scratch:
  ushort* d2   = (ushort*)dout;        // bf16 [M][1024], dead after scan; final GEMM overwrites
  float*  obuf = dout + 16777216;      // f32 [M][1024], dead after epilogue; v_first copy overwrites

  // -- transpose/convert all weights to bf16 [N][K]
  TransPack tp;
  const float* tsrc[12] = {(const float*)d_in[3],(const float*)d_in[4],(const float*)d_in[5],(const float*)d_in[6],
                           (const float*)d_in[7],(const float*)d_in[10],(const float*)d_in[13],(const float*)d_in[16],
                           (const float*)d_in[8],(const float*)d_in[11],(const float*)d_in[14],(const float*)d_in[17]};
  ushort* tdst[12] = {WrT,WkT,WvT,WoT,w1T,a1T,v1T,g1T,w2T,a2T,v2T,g2T};
  int tK[12] = {1024,1024,1024,1024,1024,1024,1024,1024,64,64,32,160};
  int tN[12] = {1024,1024,1024,1024,64,64,32,160,1024,1024,1024,1024};
  int cum = 0;
  for (int i = 0; i < 12; i++) {
    tp.d[i].src = tsrc[i]; tp.d[i].dst = tdst[i];
    tp.d[i].K = tK[i]; tp.d[i].N = tN[i];
    tp.d[i].blk0 = cum; tp.d[i].ntn = (tN[i]+31)/32;
    cum += ((tK[i]+31)/32) * ((tN[i]+31)/32);
  }
  hipLaunchKernelGGL(trans_kernel, dim3(cum), dim3(256), 0, stream, tp);

  #define GEMM_MIX(OM, coef, Bt, C, N) \
    hipLaunchKernelGGL((gemm_kernel<true, OM>), dim3(((N)+127)/128, M_/128), dim3(256), 0, stream, \
                       x, coef, (const ushort*)nullptr, Bt, (void*)(C), N, 1024)
  #define GEMM_PLAIN(OM, A, Bt, C, N, K) \
    hipLaunchKernelGGL((gemm_kernel<false, OM>), dim3(((N)+127)/128, M_/128), dim3(256), 0, stream, \
                       (const float*)nullptr, (const float*)nullptr, A, Bt, (void*)(C), N, K)

  // x_x rows: 0 r,1 w,2 k,3 v,4 a,5 g
  GEMM_MIX(1, xx + 0*1024, WrT, rb, 1024);
  GEMM_MIX(1, xx + 2*1024, WkT, kb, 1024);
  GEMM_MIX(1, xx + 3*1024, WvT, vb, 1024);
  GEMM_MIX(2, xx + 1*1024, w1T, d1b, 64);     // tanh
  GEMM_MIX(1, xx + 4*1024, a1T, a1b, 64);
  GEMM_MIX(1, xx + 3*1024, v1T, v1b, 32);
  GEMM_MIX(3, xx + 5*1024, g1T, g1b, 160);    // sigmoid

  GEMM_PLAIN(1, d1b, w2T, d2,  1024, 64);
  GEMM_PLAIN(1, a1b, a2T, a2o, 1024, 64);
  GEMM_PLAIN(1, v1b, v2T, v2o, 1024, 32);
  GEMM_PLAIN(1, g1b, g2T, gio, 1024, 160);

  hipLaunchKernelGGL(scan_kernel, dim3(B_*H_), dim3(256), 0, stream,
                     rb, kb, vb, d2, a2o, v2o, vfirst, w0v, a0v, v0v, kkv, kav, obuf);

  hipLaunchKernelGGL(epilogue_kernel, dim3(M_), dim3(256), 0, stream,
                     obuf, rb, kb, vb, a2o, v2o, vfirst, gio, a0v, v0v, kav, rkv, gnw, gnb);

  GEMM_PLAIN(0, gio, WoT, dout, 1024, 1024);  // writes out[0 : 16M floats)

  hipMemcpyAsync(dout + 16777216, d_in[1], (size_t)16777216*4, hipMemcpyDeviceToDevice, stream);
}